// Round 14
// baseline (131.395 us; speedup 1.0000x reference)
//
#include <hip/hip_runtime.h>
#include <hip/hip_bf16.h>
#include <stdint.h>

// fp32 in / fp32 out; bf16 MFMA internally (threshold 6.6e-2 >> bf16 quant err)
// Round 14: champion R7 structure with ONE change — LDS = bare double buffer
// (46336 B) so 3 blocks/CU fit. Epilogue transpose reuses the DEAD current
// A-buffer as scratch (raw s_barrier first; staging DMAs stay in flight).
#define M_ROWS (4*128*512)   // 262144 flattened (b,s,n) rows
#define FDIM 362
#define TROWS 16             // rows per tile (one 16x16x32 A-frag)
#define ROWB 1448            // bytes per fp32 row
#define TILEB (TROWS*ROWB)   // 23168 B per tile buffer
#define CPW 362              // 16B chunks per wave (4*362 = TILEB/16)
#define NTILES (M_ROWS/TROWS)// 16384
#define GRID 768             // 3 blocks/CU co-resident; grid-stride
#define OUT_HALF 16777216    // M_ROWS*64

typedef __attribute__((ext_vector_type(8))) short bf16x8;
typedef __attribute__((ext_vector_type(4))) float f32x4;

__device__ __forceinline__ float2 ld2(const float* p) { return *(const float2*)p; }

__device__ __forceinline__ bf16x8 pack8(float2 a, float2 b, float2 c, float2 d) {
  union { __hip_bfloat162 h[4]; bf16x8 v; } t;
  t.h[0] = __float22bfloat162_rn(a);
  t.h[1] = __float22bfloat162_rn(b);
  t.h[2] = __float22bfloat162_rn(c);
  t.h[3] = __float22bfloat162_rn(d);
  return t.v;
}

__global__ __launch_bounds__(256, 3) void dfl_kernel(
    const float* __restrict__ x,
    const float* __restrict__ Wg,
    const float* __restrict__ Wgb,
    const float* __restrict__ Wh,
    const float* __restrict__ Whb,
    float* __restrict__ out)
{
  // ONLY the double-buffered fp32 A tiles: 46336 B total -> 3 blocks/CU
  __shared__ __attribute__((aligned(16))) unsigned char Ab[2][TILEB];

  const int tid  = threadIdx.x;
  const int lane = tid & 63;
  const int wv   = tid >> 6;       // 4 fat waves = 4 col-slabs: g0 g1 h0 h1
  const int q    = lane >> 4;
  const int l15  = lane & 15;
  const bool is_h = wv >= 2;
  const int colb  = (wv & 1) * 32;
  const float* Wsel  = is_h ? Wh  : Wg;
  const float* Wbsel = is_h ? Whb : Wgb;

  // ---- B-fragment preload (fp32 -> bf16 regs, once per block) ----
  bf16x8 bw[2][12];
  float biasf[2], w0f[2];
#pragma unroll
  for (int f = 0; f < 2; ++f) {
    const int dloc = colb + f*16 + l15;                 // 0..63
    const float* wrow = Wsel + (size_t)dloc * FDIM;
    biasf[f] = Wbsel[dloc];
    w0f[f]   = wrow[0];
#pragma unroll
    for (int k = 0; k < 12; ++k) {
      float2 u0 = make_float2(0.f,0.f), u1 = u0, u2 = u0, u3 = u0;
      if (k < 11) {
        const float* p = wrow + k*32 + q*8;
        u0 = ld2(p); u1 = ld2(p+2); u2 = ld2(p+4); u3 = ld2(p+6);
      } else if (q == 0) {
        u0 = ld2(wrow+352); u1 = ld2(wrow+354); u2 = ld2(wrow+356); u3 = ld2(wrow+358);
      } else if (q == 1) {
        u0 = ld2(wrow+360);                              // f=360,361; rest pad 0
      }
      bw[f][k] = pack8(u0, u1, u2, u3);                  // zeros at f>=362
    }
  }

  // ---- staging: async DMA, zero VGPR cost, linear 16B-chunk copy ----
  auto stage = [&](int tile, int p) {
    const unsigned char* src = (const unsigned char*)(x + (size_t)tile * TROWS * FDIM);
    unsigned char* dst = &Ab[p][0];
#pragma unroll
    for (int j = 0; j < 6; ++j) {
      const int cbase = wv*CPW + j*64;                   // wave-uniform
      if (lane < CPW - j*64) {                           // j<5: all lanes; j=5: 42
        __builtin_amdgcn_global_load_lds(
            (const __attribute__((address_space(1))) unsigned int*)(src + (size_t)(cbase + lane)*16),
            (__attribute__((address_space(3))) unsigned int*)(dst + cbase*16),
            16, 0, 0);                                   // HW adds lane*16 to dest
      }
    }
  };

  float* outp = out + (is_h ? OUT_HALF : 0) + colb;

  int t = (int)blockIdx.x;
  stage(t, 0);
  __syncthreads();                                       // tile t staged

  for (int i = 0; t < NTILES; t += GRID, ++i) {
    const int p  = i & 1;
    const int m0 = t * TROWS;
    const int tn = t + GRID;
    if (tn < NTILES) stage(tn, p ^ 1);                   // in flight all round

    // partner feature-0 for rank-1 correction
    const float rp = x[(size_t)((m0 ^ 512) + l15) * FDIM];

    unsigned char* AbP = &Ab[p][0];
    const unsigned char* ap = AbP + l15*ROWB + q*32;

    f32x4 acc0 = {biasf[0],biasf[0],biasf[0],biasf[0]};
    f32x4 acc1 = {biasf[1],biasf[1],biasf[1],biasf[1]};
#pragma unroll
    for (int k = 0; k < 11; ++k) {
      const unsigned char* pk = ap + k*128;              // 8B-aligned ds_read_b64
      bf16x8 av = pack8(*(const float2*)pk, *(const float2*)(pk+8),
                        *(const float2*)(pk+16), *(const float2*)(pk+24));
      acc0 = __builtin_amdgcn_mfma_f32_16x16x32_bf16(av, bw[0][k], acc0, 0,0,0);
      acc1 = __builtin_amdgcn_mfma_f32_16x16x32_bf16(av, bw[1][k], acc1, 0,0,0);
    }
    { // k=11: only features 352..361 valid — masked reads, no row overrun
      const unsigned char* pk = ap + 11*128;
      float2 z2 = make_float2(0.f,0.f), f0 = z2, f1 = z2, f2 = z2, f3 = z2;
      if (q == 0) {
        f0 = *(const float2*)pk;      f1 = *(const float2*)(pk+8);
        f2 = *(const float2*)(pk+16); f3 = *(const float2*)(pk+24);
      } else if (q == 1) {
        f0 = *(const float2*)pk;                          // features 360,361
      }
      bf16x8 av = pack8(f0, f1, f2, f3);
      acc0 = __builtin_amdgcn_mfma_f32_16x16x32_bf16(av, bw[0][11], acc0, 0,0,0);
      acc1 = __builtin_amdgcn_mfma_f32_16x16x32_bf16(av, bw[1][11], acc1, 0,0,0);
    }

    // ---- rank-1 correction coefficient (lanes 0-15 hold row l15's value) ----
    const float rs = *(const float*)(AbP + l15*ROWB);    // x[row][0] from LDS
    const float cval = is_h ? -(rs + rp)*0.5f : (rp - rs)*0.5f;

    // ---- buffer p is now fully consumed by every wave (all LDS reads above
    // are data-dependency-complete). Raw s_barrier (NO vmcnt drain — staging
    // DMAs for p^1 stay in flight), then reuse p's first 8KB as the per-wave
    // transpose scratch: champion dwordx4 store path, zero extra LDS. ----
    asm volatile("s_waitcnt lgkmcnt(0)" ::: "memory");
    __builtin_amdgcn_s_barrier();
    unsigned char* wb = AbP + wv*2048;                   // wave-private 2KB
#pragma unroll
    for (int jj = 0; jj < 4; ++jj) {
      const float cc = __shfl(cval, q*4 + jj, 64);       // src lanes 0..15
      const int rl = q*4 + jj;                           // C/D row = (lane>>4)*4+reg
#pragma unroll
      for (int fn = 0; fn < 2; ++fn) {
        const float v = (fn ? acc1[jj] : acc0[jj]) + cc * w0f[fn];
        const int col = fn*16 + l15;
        const int boff = rl*128 + ((((col>>2) ^ (rl&7))) << 4) + ((col&3) << 2);
        *(float*)(wb + boff) = v;
      }
    }
#pragma unroll
    for (int s = 0; s < 2; ++s) {
      const int rr = s*8 + (lane >> 3);
      const int cs = lane & 7;
      f32x4 vv = *(const f32x4*)(wb + rr*128 + (((cs ^ (rr&7))) << 4));
      *(f32x4*)(outp + (size_t)(m0 + rr)*64 + cs*4) = vv;
    }

    __syncthreads();   // drains stage(tn) DMAs + scratch use before p overwrite
  }
}

extern "C" void kernel_launch(void* const* d_in, const int* in_sizes, int n_in,
                              void* d_out, int out_size, void* d_ws, size_t ws_size,
                              hipStream_t stream) {
  (void)in_sizes; (void)n_in; (void)d_ws; (void)ws_size; (void)out_size;
  const float* x   = (const float*)d_in[0];
  const float* Wg  = (const float*)d_in[1];
  const float* Wgb = (const float*)d_in[2];
  const float* Wh  = (const float*)d_in[3];
  const float* Whb = (const float*)d_in[4];
  float* out = (float*)d_out;
  dfl_kernel<<<GRID, 256, 0, stream>>>(x, Wg, Wgb, Wh, Whb, out);
}

// Round 15
// 113.051 us; speedup vs baseline: 1.1623x; 1.1623x over previous
//
#include <hip/hip_runtime.h>
#include <hip/hip_bf16.h>
#include <stdint.h>

// fp32 in / fp32 out; bf16 MFMA internally (threshold 6.6e-2 >> bf16 quant err)
// Round 15: EXACT restore of the R7 champion (116.3 µs) — double-buffered
// LDS-DMA staging, 4 fat waves, strided tile order, __syncthreads — with one
// change: nontemporal epilogue stores (output is write-once; keep L2 for x).
#define M_ROWS (4*128*512)   // 262144 flattened (b,s,n) rows
#define FDIM 362
#define KSTEPS 12            // K padded to 384 = 12*32
#define TROWS 16             // rows per tile (one 16x16x32 A-frag)
#define ROWB 1448            // bytes per fp32 row
#define TILEB (TROWS*ROWB)   // 23168 B per tile buffer
#define GRID 1024
#define TPB 16               // 1024*16*16 = 262144 rows
#define OUT_HALF 16777216    // M_ROWS*64

typedef __attribute__((ext_vector_type(8))) short bf16x8;
typedef __attribute__((ext_vector_type(4))) float f32x4;

__device__ __forceinline__ float2 ld2(const float* p) { return *(const float2*)p; }

__device__ __forceinline__ bf16x8 pack8(float2 a, float2 b, float2 c, float2 d) {
  union { __hip_bfloat162 h[4]; bf16x8 v; } t;
  t.h[0] = __float22bfloat162_rn(a);
  t.h[1] = __float22bfloat162_rn(b);
  t.h[2] = __float22bfloat162_rn(c);
  t.h[3] = __float22bfloat162_rn(d);
  return t.v;
}

__global__ __launch_bounds__(256, 2) void dfl_kernel(
    const float* __restrict__ x,
    const float* __restrict__ Wg,
    const float* __restrict__ Wgb,
    const float* __restrict__ Wh,
    const float* __restrict__ Whb,
    float* __restrict__ out)
{
  // double-buffered fp32 A tile (linear copy of 23168B) + per-wave transpose buf
  __shared__ __attribute__((aligned(16))) unsigned char Ab[2][TILEB]; // 46336 B
  __shared__ __attribute__((aligned(16))) unsigned char tb[4*2048];   // 8 KiB

  const int tid  = threadIdx.x;
  const int lane = tid & 63;
  const int wv   = tid >> 6;       // 4 waves = 4 col-slabs: g0 g1 h0 h1
  const int q    = lane >> 4;
  const int l15  = lane & 15;
  const bool is_h = wv >= 2;
  const int colb  = (wv & 1) * 32;
  const float* Wsel  = is_h ? Wh  : Wg;
  const float* Wbsel = is_h ? Whb : Wgb;

  // ---- B-fragment preload (fp32 -> bf16 regs, once per block) ----
  bf16x8 bw[2][KSTEPS];
  float biasf[2], w0f[2];
#pragma unroll
  for (int f = 0; f < 2; ++f) {
    const int dloc = colb + f*16 + l15;                 // 0..63
    const float* wrow = Wsel + (size_t)dloc * FDIM;
    biasf[f] = Wbsel[dloc];
    w0f[f]   = wrow[0];
#pragma unroll
    for (int k = 0; k < KSTEPS; ++k) {
      float2 t0 = make_float2(0.f,0.f), t1 = t0, t2 = t0, t3 = t0;
      if (k < 11) {
        const float* p = wrow + k*32 + q*8;
        t0 = ld2(p); t1 = ld2(p+2); t2 = ld2(p+4); t3 = ld2(p+6);
      } else if (q == 0) {
        t0 = ld2(wrow+352); t1 = ld2(wrow+354); t2 = ld2(wrow+356); t3 = ld2(wrow+358);
      } else if (q == 1) {
        t0 = ld2(wrow+360);                              // f=360,361; rest pad 0
      }
      bw[f][k] = pack8(t0, t1, t2, t3);                  // zeros at f>=362
    }
  }

  // zero the 96B k=11 overrun pad once (row15 reads <=88B past buffer 0 into
  // Ab[1]; after the first staging round that region always holds finite x data)
  if (tid < 6) *(f32x4*)(&Ab[1][0] + tid*16) = (f32x4){0.f,0.f,0.f,0.f};

  // ---- staging: async DMA, zero VGPR cost — linear 16B-chunk copy ----
  auto stage = [&](int tile, int p) {
    const unsigned char* src = (const unsigned char*)(x + (size_t)tile * TROWS * FDIM);
    unsigned char* dst = &Ab[p][0];
#pragma unroll
    for (int j = 0; j < 6; ++j) {
      const int chunk = wv*384 + j*64 + lane;            // 16B chunk index
      if (chunk < TILEB/16) {
        __builtin_amdgcn_global_load_lds(
            (const __attribute__((address_space(1))) unsigned int*)(src + (size_t)chunk*16),
            (__attribute__((address_space(3))) unsigned int*)(dst + (wv*384 + j*64)*16),
            16, 0, 0);                                   // HW adds lane*16 to LDS dest
      }
    }
  };

  unsigned char* wb = tb + wv*2048;
  float* outp = out + (is_h ? OUT_HALF : 0) + colb;

  stage((int)blockIdx.x, 0);
  __syncthreads();                                       // vmcnt(0): tile 0 staged

  for (int i = 0; i < TPB; ++i) {
    const int p  = i & 1;
    const int m0 = ((int)blockIdx.x + i*GRID) * TROWS;
    if (i + 1 < TPB) stage((int)blockIdx.x + (i+1)*GRID, p ^ 1);  // in flight all tile

    // partner feature-0 for rank-1 correction (latency hidden under K-loop)
    float rp = 0.f;
    if (lane < 16) rp = x[(size_t)((m0 ^ 512) + l15) * FDIM];

    const unsigned char* AbP = &Ab[p][0];
    const unsigned char* ap  = AbP + l15*ROWB + q*32;

    f32x4 acc0 = {biasf[0],biasf[0],biasf[0],biasf[0]};
    f32x4 acc1 = {biasf[1],biasf[1],biasf[1],biasf[1]};
#pragma unroll
    for (int k = 0; k < KSTEPS; ++k) {
      const unsigned char* pk = ap + k*128;              // 8B-aligned ds_read_b64 x4
      float2 f0 = *(const float2*)(pk);
      float2 f1 = *(const float2*)(pk + 8);
      float2 f2 = *(const float2*)(pk + 16);
      float2 f3 = *(const float2*)(pk + 24);
      // k=11 reads <=88B past row end: finite garbage x bw-zeros = 0
      bf16x8 av = pack8(f0, f1, f2, f3);
      acc0 = __builtin_amdgcn_mfma_f32_16x16x32_bf16(av, bw[0][k], acc0, 0,0,0);
      acc1 = __builtin_amdgcn_mfma_f32_16x16x32_bf16(av, bw[1][k], acc1, 0,0,0);
    }

    // ---- rank-1 correction coefficient (lanes 0-15 hold row l15's value) ----
    const float rs = *(const float*)(AbP + l15*ROWB);    // x[row][0] from LDS
    const float cval = is_h ? -(rs + rp)*0.5f : (rp - rs)*0.5f;

    // ---- epilogue: correction fma, transpose via wave-private LDS ----
#pragma unroll
    for (int jj = 0; jj < 4; ++jj) {
      const float cc = __shfl(cval, q*4 + jj, 64);       // src lanes 0..15
      const int rl = q*4 + jj;                           // C/D: row=(lane>>4)*4+reg
#pragma unroll
      for (int fn = 0; fn < 2; ++fn) {
        const float v = (fn ? acc1[jj] : acc0[jj]) + cc * w0f[fn];
        const int col = fn*16 + l15;
        const int boff = rl*128 + ((((col>>2) ^ (rl&7))) << 4) + ((col&3) << 2);
        *(float*)(wb + boff) = v;
      }
    }
    // read back row-major: 8 lanes x 16B = 128B per output-row segment.
    // Nontemporal: output is write-once, never re-read — don't pollute L2.
#pragma unroll
    for (int s = 0; s < 2; ++s) {
      const int rr = s*8 + (lane >> 3);
      const int cs = lane & 7;
      f32x4 vv = *(const f32x4*)(wb + rr*128 + (((cs ^ (rr&7))) << 4));
      __builtin_nontemporal_store(vv, (f32x4*)(outp + (size_t)(m0 + rr)*64 + cs*4));
    }

    __syncthreads();   // drains stage(i+1) DMAs + all buf-p reads before overwrite
  }
}

extern "C" void kernel_launch(void* const* d_in, const int* in_sizes, int n_in,
                              void* d_out, int out_size, void* d_ws, size_t ws_size,
                              hipStream_t stream) {
  (void)in_sizes; (void)n_in; (void)d_ws; (void)ws_size; (void)out_size;
  const float* x   = (const float*)d_in[0];
  const float* Wg  = (const float*)d_in[1];
  const float* Wgb = (const float*)d_in[2];
  const float* Wh  = (const float*)d_in[3];
  const float* Whb = (const float*)d_in[4];
  float* out = (float*)d_out;
  dfl_kernel<<<GRID, 256, 0, stream>>>(x, Wg, Wgb, Wh, Whb, out);
}